// Round 20
// baseline (171.651 us; speedup 1.0000x reference)
//
#include <hip/hip_runtime.h>
#include <hip/hip_bf16.h>

#define B_   2
#define N_   2048
#define C_   1152
#define NH   16
#define HD   72
#define HDP  96    // padded head dim for QK^T (3 x K=32)
#define HDV  80    // padded head dim for PV (5 x 16)
#define QSTR 3584  // padded QKV row stride (3456 -> 28 x 128)
#define KROW 104   // K LDS row stride (96 data + 8 pad shorts) -> 2-way reads
#define VROW 72    // V LDS row stride (64 data + 8 pad shorts) -> 2-way reads
#define KVB  64    // keys per attention tile (triple-buffered)
#define KCH  832   // K chunks (64 rows x 13)
#define TCH  1552  // total chunks per tile (K 832 + V 720)
#define WCH  388   // chunks per wave (1552/4)

typedef __attribute__((ext_vector_type(8))) short bf16x8;
typedef __attribute__((ext_vector_type(4))) float f32x4;

__device__ __forceinline__ short f2bf(float f) {
  union { float fv; unsigned int u; } v; v.fv = f;
  unsigned int r = v.u + 0x7fffu + ((v.u >> 16) & 1u);
  return (short)(r >> 16);
}

__device__ __forceinline__ float bf2f(short s) {
  union { unsigned u; float f; } v; v.u = ((unsigned)(unsigned short)s) << 16;
  return v.f;
}

__device__ __forceinline__ unsigned pack_bf16(float a, float b) {
  union { __hip_bfloat162 h; unsigned u; } c;
  c.h = __float22bfloat162_rn(make_float2(a, b));
  return c.u;
}

__device__ __forceinline__ void gload_lds16(const short* g, short* l) {
  __builtin_amdgcn_global_load_lds(
      (const __attribute__((address_space(1))) unsigned int*)g,
      (__attribute__((address_space(3))) unsigned int*)l, 16, 0, 0);
}

// ---------------- fused prep: x->bf16, Wqkv^T (pad), Wproj^T, RoPE trig table ----------------
__global__ __launch_bounds__(256) void prep(
    const float* __restrict__ x, short* __restrict__ xb,
    const float* __restrict__ Wqkv, short* __restrict__ Wt,
    const float* __restrict__ Wproj, short* __restrict__ Wpt,
    float2* __restrict__ trig) {
  int bid = blockIdx.x;
  if (bid < 4608) {
    const int i = bid * 256 + threadIdx.x;
    float4 v = ((const float4*)x)[i];
    short4 s;
    s.x = f2bf(v.x); s.y = f2bf(v.y); s.z = f2bf(v.z); s.w = f2bf(v.w);
    ((short4*)xb)[i] = s;
    return;
  }
  bid -= 4608;
  if (bid >= 4032 + 1296) {  // trig table: 192 blocks, 2048*24 entries
    const int idx = (bid - 4032 - 1296) * 256 + threadIdx.x;
    const int n = idx / 24, p = idx - (idx / 24) * 24;
    const float PI = 3.14159265358979323846f;
    float pos;
    if (p < 8)       pos = -1.f + (2.f / 7.f)  * (float)(n >> 8);
    else if (p < 16) pos = -1.f + (2.f / 15.f) * (float)((n >> 4) & 15);
    else             pos = -1.f + (2.f / 15.f) * (float)(n & 15);
    const float base = (1.f + (127.f / 7.f) * (float)(p & 7)) * PI;
    const float f = pos * base;
    trig[idx] = make_float2(cosf(f), sinf(f));
    return;
  }
  const float* src; short* dst; int Cc, bx, by;
  if (bid < 4032) {
    bx = bid % 112; by = bid / 112; src = Wqkv; dst = Wt; Cc = 3456;
  } else {
    bid -= 4032;
    bx = bid % 36; by = bid / 36; src = Wproj; dst = Wpt; Cc = 1152;
  }
  __shared__ float tile[32][33];
  const int c0 = bx * 32, r0 = by * 32;
  const int tx = threadIdx.x & 31, ty = threadIdx.x >> 5;
  for (int i = ty; i < 32; i += 8)
    tile[i][tx] = (c0 + tx < Cc) ? src[(long)(r0 + i) * Cc + c0 + tx] : 0.f;
  __syncthreads();
  for (int i = ty; i < 32; i += 8)
    dst[(long)(c0 + i) * 1152 + r0 + tx] = f2bf(tile[tx][i]);
}

// ---------------- GEMM 128^2 (counted-vmcnt raw-barrier dbuf, natural occupancy) ----------------
template<bool BIAS, bool OBF>
__global__ __launch_bounds__(256, 2) void gemm_bt(
    const short* __restrict__ A, const short* __restrict__ Bt,
    void* __restrict__ Cv, const float* __restrict__ bias,
    int M, int N, int K) {
  __shared__ __align__(16) short As[2][128 * 32];
  __shared__ __align__(16) short Bs[2][128 * 32];
  const int t = threadIdx.x;
  const int lane = t & 63, wid = t >> 6;
  const int fr = lane & 15, fq = lane >> 4;

  int lin = blockIdx.y * gridDim.x + blockIdx.x;
  const int q8 = (int)(gridDim.x * gridDim.y) >> 3;
  lin = (lin & 7) * q8 + (lin >> 3);
  const int bm = lin / (int)gridDim.x;
  const int bn = lin - bm * (int)gridDim.x;

  const int wr = (wid >> 1) * 64, wc = (wid & 1) * 64;

  const int srow = t >> 2;
  const int scol = (t & 3) * 8;
  const short* Ag = A + (long)(bm * 128 + srow) * K + scol;
  const short* Bg = Bt + (long)(bn * 128 + srow) * K + scol;

  f32x4 acc[4][4] = {};

  auto STAGE = [&](int kt, int bufi) {
    gload_lds16(Ag + kt * 32,                &As[bufi][t * 8]);
    gload_lds16(Ag + kt * 32 + (long)64 * K, &As[bufi][2048 + t * 8]);
    gload_lds16(Bg + kt * 32,                &Bs[bufi][t * 8]);
    gload_lds16(Bg + kt * 32 + (long)64 * K, &Bs[bufi][2048 + t * 8]);
  };

  const int NKT = K / 32;
  STAGE(0, 0);

  for (int kt = 0; kt < NKT; ++kt) {
    const int cur = kt & 1;
    if (kt + 1 < NKT) {
      STAGE(kt + 1, cur ^ 1);
      asm volatile("s_waitcnt vmcnt(4)" ::: "memory");
    } else {
      asm volatile("s_waitcnt vmcnt(0)" ::: "memory");
    }
    __builtin_amdgcn_s_barrier();

    bf16x8 af[4], bf[4];
    #pragma unroll
    for (int i = 0; i < 4; ++i)
      af[i] = *(const bf16x8*)(&As[cur][(wr + i * 16 + fr) * 32 + fq * 8]);
    #pragma unroll
    for (int j = 0; j < 4; ++j)
      bf[j] = *(const bf16x8*)(&Bs[cur][(wc + j * 16 + fr) * 32 + fq * 8]);
    __builtin_amdgcn_s_setprio(1);
    #pragma unroll
    for (int i = 0; i < 4; ++i)
      #pragma unroll
      for (int j = 0; j < 4; ++j)
        acc[i][j] = __builtin_amdgcn_mfma_f32_16x16x32_bf16(af[i], bf[j], acc[i][j], 0, 0, 0);
    __builtin_amdgcn_s_setprio(0);
    __builtin_amdgcn_s_barrier();
  }

  #pragma unroll
  for (int i = 0; i < 4; ++i) {
    #pragma unroll
    for (int j = 0; j < 4; ++j) {
      const long row0 = (long)bm * 128 + wr + i * 16 + fq * 4;
      const int col = bn * 128 + wc + j * 16 + fr;
      const float bv = BIAS ? bias[col] : 0.f;
      #pragma unroll
      for (int r = 0; r < 4; ++r) {
        const float val = acc[i][j][r] + bv;
        if constexpr (OBF)
          ((short*)Cv)[(row0 + r) * (long)N + col] = f2bf(val);
        else
          ((float*)Cv)[(row0 + r) * (long)N + col] = val;
      }
    }
  }
}

// ---------------- RoPE + repack: K (rope via table) + V (transpose, pi-permuted) ----------------
__global__ __launch_bounds__(256) void rope_pack(
    const short* __restrict__ QKV, const float2* __restrict__ trig,
    short* __restrict__ Kp, short* __restrict__ Vt) {
  const int blk = blockIdx.x;
  const int nt = blk & 15;
  const int h = (blk >> 4) & 15;
  const int b = blk >> 8;
  const int t = threadIdx.x;
  const int n0 = nt * 128;
  const long bhn = ((long)(b * NH + h)) * N_;

  for (int idx = t; idx < 128 * 48; idx += 256) {
    const int r = idx / 48;
    const int p = idx - r * 48;
    const int n = n0 + r;
    float vx = 0.f, vy = 0.f;
    if (p < 36) {
      short2 v2 = *(const short2*)(QKV + ((long)(b * N_ + n)) * QSTR + C_ + h * HD + 2 * p);
      vx = bf2f(v2.x); vy = bf2f(v2.y);
    }
    float o0 = vx, o1 = vy;
    if (p < 24) {
      const float2 cs = trig[n * 24 + p];
      o0 = vx * cs.x - vy * cs.y;
      o1 = vy * cs.x + vx * cs.y;
    }
    short2 ov; ov.x = f2bf(o0); ov.y = f2bf(o1);
    *(short2*)(Kp + (bhn + n) * HDP + 2 * p) = ov;
  }

  __shared__ short vt[128][82];
  for (int idx = t; idx < 128 * 40; idx += 256) {
    const int r = idx / 40, p = idx - r * 40;
    short2 v2; v2.x = 0; v2.y = 0;
    if (p < 36)
      v2 = *(const short2*)(QKV + ((long)(b * N_ + n0 + r)) * QSTR + 2 * C_ + h * HD + 2 * p);
    *(short2*)(&vt[r][2 * p]) = v2;
  }
  __syncthreads();
  for (int idx = t; idx < HDV * 128; idx += 256) {
    const int d = idx >> 7, nn = idx & 127;
    const int c = nn & 31;
    const int nsrc = (nn & 96) | (((c >> 2) & 1) * 16 + ((c >> 3) & 3) * 4 + (c & 3));
    Vt[(((long)(b * NH + h)) * HDV + d) * N_ + n0 + nn] = vt[nsrc][d];
  }
}

// ---------------- flash attention: triple-buffered KV + 2-deep s-pipeline, Q-RoPE via table ----------------
#define QKT_STEP(BUFI, S)                                                      \
  {                                                                            \
    const short* KsC_ = &KV[(BUFI)][0];                                        \
    __builtin_amdgcn_s_setprio(1);                                             \
    _Pragma("unroll")                                                          \
    for (int j = 0; j < 4; ++j) {                                              \
      _Pragma("unroll")                                                        \
      for (int kk = 0; kk < 3; ++kk) {                                         \
        bf16x8 kf = *(const bf16x8*)(KsC_ + (j * 16 + fr) * KROW + (kk * 4 + fq) * 8); \
        S[0][j] = __builtin_amdgcn_mfma_f32_16x16x32_bf16(kf, qf[0][kk], S[0][j], 0, 0, 0); \
        S[1][j] = __builtin_amdgcn_mfma_f32_16x16x32_bf16(kf, qf[1][kk], S[1][j], 0, 0, 0); \
      }                                                                        \
    }                                                                          \
    __builtin_amdgcn_s_setprio(0);                                             \
  }

#define ATTN_STEP(T, SCUR, SNEXT)                                              \
  {                                                                            \
    const int t_ = (T);                                                        \
    _Pragma("unroll")                                                          \
    for (int i = 0; i < 2; ++i) {                                              \
      float psum = 0.f;                                                        \
      _Pragma("unroll")                                                        \
      for (int j = 0; j < 4; ++j)                                              \
        _Pragma("unroll")                                                      \
        for (int r = 0; r < 4; ++r) {                                          \
          const float p = __builtin_amdgcn_exp2f(SCUR[i][j][r]);               \
          SCUR[i][j][r] = p;                                                   \
          psum += p;                                                           \
        }                                                                      \
      l_[i] += psum;                                                           \
    }                                                                          \
    asm volatile("s_waitcnt vmcnt(0)" ::: "memory");                           \
    __builtin_amdgcn_s_barrier();                                              \
    if (t_ + 2 < 32) STAGE(t_ + 2, (t_ + 2) % 3);                              \
    if (t_ + 1 < 32) {                                                         \
      _Pragma("unroll")                                                        \
      for (int i = 0; i < 2; ++i)                                              \
        _Pragma("unroll")                                                      \
        for (int j = 0; j < 4; ++j)                                            \
          SNEXT[i][j] = (f32x4){0.f, 0.f, 0.f, 0.f};                           \
      QKT_STEP((t_ + 1) % 3, SNEXT);                                           \
    }                                                                          \
    const short* VsC_ = &KV[t_ % 3][KCH * 8];                                  \
    __builtin_amdgcn_s_setprio(1);                                             \
    _Pragma("unroll")                                                          \
    for (int g = 0; g < 2; ++g) {                                              \
      union { unsigned u[4]; bf16x8 v; } pf0, pf1;                             \
      pf0.u[0] = pack_bf16(SCUR[0][2 * g][0],     SCUR[0][2 * g][1]);          \
      pf0.u[1] = pack_bf16(SCUR[0][2 * g][2],     SCUR[0][2 * g][3]);          \
      pf0.u[2] = pack_bf16(SCUR[0][2 * g + 1][0], SCUR[0][2 * g + 1][1]);      \
      pf0.u[3] = pack_bf16(SCUR[0][2 * g + 1][2], SCUR[0][2 * g + 1][3]);      \
      pf1.u[0] = pack_bf16(SCUR[1][2 * g][0],     SCUR[1][2 * g][1]);          \
      pf1.u[1] = pack_bf16(SCUR[1][2 * g][2],     SCUR[1][2 * g][3]);          \
      pf1.u[2] = pack_bf16(SCUR[1][2 * g + 1][0], SCUR[1][2 * g + 1][1]);      \
      pf1.u[3] = pack_bf16(SCUR[1][2 * g + 1][2], SCUR[1][2 * g + 1][3]);      \
      _Pragma("unroll")                                                        \
      for (int jd = 0; jd < 5; ++jd) {                                         \
        bf16x8 vf = *(const bf16x8*)(VsC_ + (jd * 16 + fr) * VROW + (g * 4 + fq) * 8); \
        accO[0][jd] = __builtin_amdgcn_mfma_f32_16x16x32_bf16(pf0.v, vf, accO[0][jd], 0, 0, 0); \
        accO[1][jd] = __builtin_amdgcn_mfma_f32_16x16x32_bf16(pf1.v, vf, accO[1][jd], 0, 0, 0); \
      }                                                                        \
    }                                                                          \
    __builtin_amdgcn_s_setprio(0);                                             \
  }

__global__ __launch_bounds__(256, 2) void attn(
    const short* __restrict__ QKVb, const short* __restrict__ Kp,
    const short* __restrict__ Vt, const float2* __restrict__ trig,
    short* __restrict__ Aproj) {
  __shared__ __align__(16) short KV[3][TCH * 8];  // 3 x 24.25 KB
  int blk = blockIdx.x;
  blk = (blk & 7) * 64 + (blk >> 3);
  const int qt = blk & 15;
  const int h = (blk >> 4) & 15;
  const int b = blk >> 8;
  const int t = threadIdx.x, lane = t & 63, wid = t >> 6;
  const int fr = lane & 15, fq = lane >> 4;

  const long bh = (long)(b * NH + h);
  const short* Kg = Kp + bh * N_ * HDP;
  const short* Vg = Vt + bh * HDV * N_;

  const short* sb[7];
  int sstr[7];
  #pragma unroll
  for (int it = 0; it < 7; ++it) {
    int g = wid * WCH + (it < 6 ? it * 64 + lane : 384 + lane);
    if (g >= TCH) g = TCH - 1;
    if (g < KCH) {
      const int r = g / 13, c = g - r * 13;
      sb[it] = Kg + r * HDP + (c < 12 ? c * 8 : 0);
      sstr[it] = KVB * HDP;
    } else {
      const int v = g - KCH;
      const int r = v / 9, c = v - r * 9;
      sb[it] = Vg + r * N_ + (c < 8 ? c * 8 : 0);
      sstr[it] = KVB;
    }
  }

  f32x4 accO[2][5] = {};
  float l_[2] = {0.f, 0.f};

  auto STAGE = [&](int kt, int bufi) {
    short* D = &KV[bufi][0];
    #pragma unroll
    for (int it = 0; it < 6; ++it)
      gload_lds16(sb[it] + kt * sstr[it], D + (wid * WCH + it * 64 + lane) * 8);
    if (lane < 4)
      gload_lds16(sb[6] + kt * sstr[6], D + (wid * WCH + 384 + lane) * 8);
  };

  // ---- Q staging into KV[2] (free until STAGE(2,2)) ----
  {
    short* QD = &KV[2][0];
    #pragma unroll
    for (int it = 0; it < 5; ++it) {
      const int g = wid * 288 + (it < 4 ? it * 64 + lane : 256 + (lane & 31));
      const int r = g / 9, c = g - r * 9;
      const short* src = QKVb + ((long)(b * N_ + qt * 128 + r)) * QSTR + h * HD + (c < 8 ? c * 8 : 64);
      if (it < 4 || lane < 32)
        gload_lds16(src, QD + g * 8);
    }
  }
  STAGE(0, 0);
  STAGE(1, 1);
  asm volatile("s_waitcnt vmcnt(14)" ::: "memory");  // Q's 5 loads landed
  __builtin_amdgcn_s_barrier();

  // ---- build qf from LDS Q tile; rope via precomputed trig table ----
  const float qscale = 0.17002324f;  // (1/sqrt(72)) * log2(e)
  bf16x8 qf[2][3];
  {
    const short* Qlds = &KV[2][0];
    #pragma unroll
    for (int i = 0; i < 2; ++i) {
      const int n = qt * 128 + wid * 32 + i * 16 + fr;
      const int lrow = wid * 32 + i * 16 + fr;
      #pragma unroll
      for (int kk = 0; kk < 3; ++kk) {
        const int col = kk * 32 + fq * 8;
        union { short s[8]; bf16x8 v; } raw;
        if (col < HD)
          raw.v = *(const bf16x8*)(Qlds + lrow * 72 + col);
        else
          #pragma unroll
          for (int z = 0; z < 8; ++z) raw.s[z] = 0;
        union { short s[8]; bf16x8 v; } outv;
        #pragma unroll
        for (int e = 0; e < 4; ++e) {
          const int p = kk * 16 + fq * 4 + e;
          const float vx = bf2f(raw.s[2 * e]), vy = bf2f(raw.s[2 * e + 1]);
          float o0 = vx, o1 = vy;
          if (p < 24) {
            const float2 cs = trig[n * 24 + p];
            o0 = vx * cs.x - vy * cs.y;
            o1 = vy * cs.x + vx * cs.y;
          }
          outv.s[2 * e]     = f2bf(o0 * qscale);
          outv.s[2 * e + 1] = f2bf(o1 * qscale);
        }
        qf[i][kk] = outv.v;
      }
    }
  }

  asm volatile("s_waitcnt vmcnt(7)" ::: "memory");  // tile-0 loads landed
  __builtin_amdgcn_s_barrier();                     // all waves done reading KV[2] as Q

  f32x4 sA[2][4], sB[2][4];
  #pragma unroll
  for (int i = 0; i < 2; ++i)
    #pragma unroll
    for (int j = 0; j < 4; ++j)
      sA[i][j] = (f32x4){0.f, 0.f, 0.f, 0.f};
  QKT_STEP(0, sA);

  for (int kt2 = 0; kt2 < 16; ++kt2) {
    ATTN_STEP(2 * kt2,     sA, sB);
    ATTN_STEP(2 * kt2 + 1, sB, sA);
  }

  #pragma unroll
  for (int i = 0; i < 2; ++i) {
    l_[i] += __shfl_xor(l_[i], 16);
    l_[i] += __shfl_xor(l_[i], 32);
  }
  float linv[2] = {1.f / l_[0], 1.f / l_[1]};
  #pragma unroll
  for (int i = 0; i < 2; ++i) {
    float li[4];
    #pragma unroll
    for (int r = 0; r < 4; ++r) li[r] = __shfl(linv[i], fq * 4 + r);
    #pragma unroll
    for (int r = 0; r < 4; ++r) {
      const long n = qt * 128 + wid * 32 + i * 16 + fq * 4 + r;
      #pragma unroll
      for (int jd = 0; jd < 5; ++jd) {
        const int d = jd * 16 + fr;
        if (d < HD)
          Aproj[((long)b * N_ + n) * C_ + h * HD + d] = f2bf(accO[i][jd][r] * li[r]);
      }
    }
  }
}

extern "C" void kernel_launch(void* const* d_in, const int* in_sizes, int n_in,
                              void* d_out, int out_size, void* d_ws, size_t ws_size,
                              hipStream_t stream) {
  const float* x     = (const float*)d_in[0];
  const float* Wqkv  = (const float*)d_in[1];
  const float* Wproj = (const float*)d_in[2];
  const float* bproj = (const float*)d_in[3];
  float* out = (float*)d_out;

  char* ws = (char*)d_ws;
  short* QKVb = (short*)ws;         size_t off = (size_t)4096 * QSTR * 2;
  short* xb  = (short*)(ws + off);  off += (size_t)4096 * 1152 * 2;
  short* Wt  = (short*)(ws + off);  off += (size_t)QSTR * 1152 * 2;
  short* Wpt = (short*)(ws + off);  off += (size_t)1152 * 1152 * 2;
  short* Kp  = (short*)(ws + off);  off += (size_t)B_ * NH * N_ * HDP * 2;
  short* Vt  = (short*)(ws + off);  off += (size_t)B_ * NH * HDV * N_ * 2;
  short* Ap  = (short*)(ws + off);  off += (size_t)4096 * 1152 * 2;
  float2* trig = (float2*)(ws + off);  off += (size_t)N_ * 24 * 8;

  prep<<<4608 + 4032 + 1296 + 192, 256, 0, stream>>>(x, xb, Wqkv, Wt, Wproj, Wpt, trig);
  gemm_bt<false, true><<<dim3(QSTR / 128, 4096 / 128), 256, 0, stream>>>(
      xb, Wt, (void*)QKVb, nullptr, 4096, QSTR, 1152);
  rope_pack<<<B_ * NH * (N_ / 128), 256, 0, stream>>>(QKVb, trig, Kp, Vt);
  attn<<<B_ * NH * (N_ / 128), 256, 0, stream>>>(QKVb, Kp, Vt, trig, Ap);
  gemm_bt<true, false><<<dim3(1152 / 128, 4096 / 128), 256, 0, stream>>>(
      Ap, Wpt, (void*)out, bproj, 4096, 1152, 1152);
}

// Round 21
// 167.641 us; speedup vs baseline: 1.0239x; 1.0239x over previous
//
#include <hip/hip_runtime.h>
#include <hip/hip_bf16.h>

#define B_   2
#define N_   2048
#define C_   1152
#define NH   16
#define HD   72
#define HDP  96    // padded head dim for QK^T (3 x K=32)
#define HDV  80    // padded head dim for PV (5 x 16)
#define QSTR 3584  // padded QKV row stride (3456 -> 14 x 256)
#define KROW 104   // K LDS row stride (96 data + 8 pad shorts) -> 2-way reads
#define VROW 72    // V LDS row stride (64 data + 8 pad shorts) -> 2-way reads
#define KVB  64    // keys per attention tile (triple-buffered)
#define KCH  832   // K chunks (64 rows x 13)
#define TCH  1552  // total chunks per tile (K 832 + V 720)
#define WCH  388   // chunks per wave (1552/4)

typedef __attribute__((ext_vector_type(8))) short bf16x8;
typedef __attribute__((ext_vector_type(4))) float f32x4;

__device__ __forceinline__ short f2bf(float f) {
  union { float fv; unsigned int u; } v; v.fv = f;
  unsigned int r = v.u + 0x7fffu + ((v.u >> 16) & 1u);
  return (short)(r >> 16);
}

__device__ __forceinline__ float bf2f(short s) {
  union { unsigned u; float f; } v; v.u = ((unsigned)(unsigned short)s) << 16;
  return v.f;
}

__device__ __forceinline__ unsigned pack_bf16(float a, float b) {
  union { __hip_bfloat162 h; unsigned u; } c;
  c.h = __float22bfloat162_rn(make_float2(a, b));
  return c.u;
}

__device__ __forceinline__ void gload_lds16(const short* g, short* l) {
  __builtin_amdgcn_global_load_lds(
      (const __attribute__((address_space(1))) unsigned int*)g,
      (__attribute__((address_space(3))) unsigned int*)l, 16, 0, 0);
}

// ---------------- fused prep: x->bf16, Wqkv^T (pad), Wproj^T, RoPE trig table ----------------
__global__ __launch_bounds__(256) void prep(
    const float* __restrict__ x, short* __restrict__ xb,
    const float* __restrict__ Wqkv, short* __restrict__ Wt,
    const float* __restrict__ Wproj, short* __restrict__ Wpt,
    float2* __restrict__ trig) {
  int bid = blockIdx.x;
  if (bid < 4608) {
    const int i = bid * 256 + threadIdx.x;
    float4 v = ((const float4*)x)[i];
    short4 s;
    s.x = f2bf(v.x); s.y = f2bf(v.y); s.z = f2bf(v.z); s.w = f2bf(v.w);
    ((short4*)xb)[i] = s;
    return;
  }
  bid -= 4608;
  if (bid >= 4032 + 1296) {  // trig table: 192 blocks, 2048*24 entries
    const int idx = (bid - 4032 - 1296) * 256 + threadIdx.x;
    const int n = idx / 24, p = idx - (idx / 24) * 24;
    const float PI = 3.14159265358979323846f;
    float pos;
    if (p < 8)       pos = -1.f + (2.f / 7.f)  * (float)(n >> 8);
    else if (p < 16) pos = -1.f + (2.f / 15.f) * (float)((n >> 4) & 15);
    else             pos = -1.f + (2.f / 15.f) * (float)(n & 15);
    const float base = (1.f + (127.f / 7.f) * (float)(p & 7)) * PI;
    const float f = pos * base;
    trig[idx] = make_float2(cosf(f), sinf(f));
    return;
  }
  const float* src; short* dst; int Cc, bx, by;
  if (bid < 4032) {
    bx = bid % 112; by = bid / 112; src = Wqkv; dst = Wt; Cc = 3456;
  } else {
    bid -= 4032;
    bx = bid % 36; by = bid / 36; src = Wproj; dst = Wpt; Cc = 1152;
  }
  __shared__ float tile[32][33];
  const int c0 = bx * 32, r0 = by * 32;
  const int tx = threadIdx.x & 31, ty = threadIdx.x >> 5;
  for (int i = ty; i < 32; i += 8)
    tile[i][tx] = (c0 + tx < Cc) ? src[(long)(r0 + i) * Cc + c0 + tx] : 0.f;
  __syncthreads();
  for (int i = ty; i < 32; i += 8)
    dst[(long)(c0 + i) * 1152 + r0 + tx] = f2bf(tile[tx][i]);
}

// ---------------- GEMM 128^2 (counted-vmcnt raw-barrier dbuf) ----------------
template<bool BIAS, bool OBF>
__global__ __launch_bounds__(256, 2) void gemm_bt(
    const short* __restrict__ A, const short* __restrict__ Bt,
    void* __restrict__ Cv, const float* __restrict__ bias,
    int M, int N, int K) {
  __shared__ __align__(16) short As[2][128 * 32];
  __shared__ __align__(16) short Bs[2][128 * 32];
  const int t = threadIdx.x;
  const int lane = t & 63, wid = t >> 6;
  const int fr = lane & 15, fq = lane >> 4;

  int lin = blockIdx.y * gridDim.x + blockIdx.x;
  const int q8 = (int)(gridDim.x * gridDim.y) >> 3;
  lin = (lin & 7) * q8 + (lin >> 3);
  const int bm = lin / (int)gridDim.x;
  const int bn = lin - bm * (int)gridDim.x;

  const int wr = (wid >> 1) * 64, wc = (wid & 1) * 64;

  const int srow = t >> 2;
  const int scol = (t & 3) * 8;
  const short* Ag = A + (long)(bm * 128 + srow) * K + scol;
  const short* Bg = Bt + (long)(bn * 128 + srow) * K + scol;

  f32x4 acc[4][4] = {};

  auto STAGE = [&](int kt, int bufi) {
    gload_lds16(Ag + kt * 32,                &As[bufi][t * 8]);
    gload_lds16(Ag + kt * 32 + (long)64 * K, &As[bufi][2048 + t * 8]);
    gload_lds16(Bg + kt * 32,                &Bs[bufi][t * 8]);
    gload_lds16(Bg + kt * 32 + (long)64 * K, &Bs[bufi][2048 + t * 8]);
  };

  const int NKT = K / 32;
  STAGE(0, 0);

  for (int kt = 0; kt < NKT; ++kt) {
    const int cur = kt & 1;
    if (kt + 1 < NKT) {
      STAGE(kt + 1, cur ^ 1);
      asm volatile("s_waitcnt vmcnt(4)" ::: "memory");
    } else {
      asm volatile("s_waitcnt vmcnt(0)" ::: "memory");
    }
    __builtin_amdgcn_s_barrier();

    bf16x8 af[4], bf[4];
    #pragma unroll
    for (int i = 0; i < 4; ++i)
      af[i] = *(const bf16x8*)(&As[cur][(wr + i * 16 + fr) * 32 + fq * 8]);
    #pragma unroll
    for (int j = 0; j < 4; ++j)
      bf[j] = *(const bf16x8*)(&Bs[cur][(wc + j * 16 + fr) * 32 + fq * 8]);
    __builtin_amdgcn_s_setprio(1);
    #pragma unroll
    for (int i = 0; i < 4; ++i)
      #pragma unroll
      for (int j = 0; j < 4; ++j)
        acc[i][j] = __builtin_amdgcn_mfma_f32_16x16x32_bf16(af[i], bf[j], acc[i][j], 0, 0, 0);
    __builtin_amdgcn_s_setprio(0);
    __builtin_amdgcn_s_barrier();
  }

  #pragma unroll
  for (int i = 0; i < 4; ++i) {
    #pragma unroll
    for (int j = 0; j < 4; ++j) {
      const long row0 = (long)bm * 128 + wr + i * 16 + fq * 4;
      const int col = bn * 128 + wc + j * 16 + fr;
      const float bv = BIAS ? bias[col] : 0.f;
      #pragma unroll
      for (int r = 0; r < 4; ++r) {
        const float val = acc[i][j][r] + bv;
        if constexpr (OBF)
          ((short*)Cv)[(row0 + r) * (long)N + col] = f2bf(val);
        else
          ((float*)Cv)[(row0 + r) * (long)N + col] = val;
      }
    }
  }
}

// ---------------- GEMM 256^2, BK=64, 8 waves, ONE barrier per K-tile ----------------
__global__ __launch_bounds__(512, 2) void gemm_bt256(
    const short* __restrict__ A, const short* __restrict__ Bt,
    short* __restrict__ Cv, int M, int N, int K) {
  __shared__ __align__(16) short As[2][256 * 64];
  __shared__ __align__(16) short Bs[2][256 * 64];
  const int t = threadIdx.x;
  const int lane = t & 63, wid = t >> 6;
  const int fr = lane & 15, fq = lane >> 4;
  const int wm = wid >> 2, wn = wid & 3;
  const int rx = fr & 7;

  int lin = blockIdx.y * gridDim.x + blockIdx.x;
  const int q8 = (int)(gridDim.x * gridDim.y) >> 3;
  lin = (lin & 7) * q8 + (lin >> 3);
  const int bm = lin / (int)gridDim.x;
  const int bn = lin - bm * (int)gridDim.x;

  int soff[4];
  #pragma unroll
  for (int r = 0; r < 4; ++r) {
    const int p = r * 512 + t;
    const int row = p >> 3, pc = p & 7;
    soff[r] = row * K + (pc ^ (row & 7)) * 8;
  }
  const short* Ag = A + (long)bm * 256 * K;
  const short* Bg = Bt + (long)bn * 256 * K;

  f32x4 acc[8][4] = {};

  const int NKT = K / 64;
  #pragma unroll
  for (int r = 0; r < 4; ++r)
    gload_lds16(Ag + soff[r], &As[0][(r * 512 + t) * 8]);
  #pragma unroll
  for (int r = 0; r < 4; ++r)
    gload_lds16(Bg + soff[r], &Bs[0][(r * 512 + t) * 8]);

  for (int kt = 0; kt < NKT; ++kt) {
    const int cur = kt & 1;
    const bool pre = (kt + 1 < NKT);
    asm volatile("s_waitcnt vmcnt(0)" ::: "memory");
    __builtin_amdgcn_s_barrier();
    const short* Ac = &As[cur][0];
    const short* Bc = &Bs[cur][0];
    bf16x8 af[4][2], bf0[2][2], bf1[2][2];

    if (pre) {
      #pragma unroll
      for (int r = 0; r < 4; ++r)
        gload_lds16(Ag + soff[r] + (kt + 1) * 64, &As[cur ^ 1][(r * 512 + t) * 8]);
    }
    #pragma unroll
    for (int i = 0; i < 4; ++i)
      #pragma unroll
      for (int kk = 0; kk < 2; ++kk)
        af[i][kk] = *(const bf16x8*)(Ac + (wm * 128 + i * 16 + fr) * 64 + (((kk * 4 + fq) ^ rx) * 8));
    #pragma unroll
    for (int j = 0; j < 2; ++j)
      #pragma unroll
      for (int kk = 0; kk < 2; ++kk)
        bf0[j][kk] = *(const bf16x8*)(Bc + (wn * 64 + j * 16 + fr) * 64 + (((kk * 4 + fq) ^ rx) * 8));
    __builtin_amdgcn_s_setprio(1);
    #pragma unroll
    for (int i = 0; i < 4; ++i)
      #pragma unroll
      for (int j = 0; j < 2; ++j)
        #pragma unroll
        for (int kk = 0; kk < 2; ++kk)
          acc[i][j] = __builtin_amdgcn_mfma_f32_16x16x32_bf16(af[i][kk], bf0[j][kk], acc[i][j], 0, 0, 0);
    __builtin_amdgcn_s_setprio(0);

    if (pre) {
      #pragma unroll
      for (int r = 0; r < 4; ++r)
        gload_lds16(Bg + soff[r] + (kt + 1) * 64, &Bs[cur ^ 1][(r * 512 + t) * 8]);
    }
    #pragma unroll
    for (int j = 0; j < 2; ++j)
      #pragma unroll
      for (int kk = 0; kk < 2; ++kk)
        bf1[j][kk] = *(const bf16x8*)(Bc + (wn * 64 + 32 + j * 16 + fr) * 64 + (((kk * 4 + fq) ^ rx) * 8));
    __builtin_amdgcn_s_setprio(1);
    #pragma unroll
    for (int i = 0; i < 4; ++i)
      #pragma unroll
      for (int j = 0; j < 2; ++j)
        #pragma unroll
        for (int kk = 0; kk < 2; ++kk)
          acc[i][2 + j] = __builtin_amdgcn_mfma_f32_16x16x32_bf16(af[i][kk], bf1[j][kk], acc[i][2 + j], 0, 0, 0);
    __builtin_amdgcn_s_setprio(0);

    #pragma unroll
    for (int i = 0; i < 4; ++i)
      #pragma unroll
      for (int kk = 0; kk < 2; ++kk)
        af[i][kk] = *(const bf16x8*)(Ac + (wm * 128 + 64 + i * 16 + fr) * 64 + (((kk * 4 + fq) ^ rx) * 8));
    __builtin_amdgcn_s_setprio(1);
    #pragma unroll
    for (int i = 0; i < 4; ++i)
      #pragma unroll
      for (int j = 0; j < 2; ++j)
        #pragma unroll
        for (int kk = 0; kk < 2; ++kk)
          acc[4 + i][j] = __builtin_amdgcn_mfma_f32_16x16x32_bf16(af[i][kk], bf0[j][kk], acc[4 + i][j], 0, 0, 0);
    __builtin_amdgcn_s_setprio(0);

    __builtin_amdgcn_s_setprio(1);
    #pragma unroll
    for (int i = 0; i < 4; ++i)
      #pragma unroll
      for (int j = 0; j < 2; ++j)
        #pragma unroll
        for (int kk = 0; kk < 2; ++kk)
          acc[4 + i][2 + j] = __builtin_amdgcn_mfma_f32_16x16x32_bf16(af[i][kk], bf1[j][kk], acc[4 + i][2 + j], 0, 0, 0);
    __builtin_amdgcn_s_setprio(0);
  }

  #pragma unroll
  for (int mi = 0; mi < 8; ++mi) {
    #pragma unroll
    for (int j = 0; j < 4; ++j) {
      const long row0 = (long)bm * 256 + wm * 128 + (mi >> 2) * 64 + (mi & 3) * 16 + fq * 4;
      const int col = bn * 256 + wn * 64 + j * 16 + fr;
      #pragma unroll
      for (int r = 0; r < 4; ++r)
        Cv[(row0 + r) * (long)N + col] = f2bf(acc[mi][j][r]);
    }
  }
}

// ---------------- RoPE + repack: K (rope via table) + V (transpose, pi-permuted) ----------------
__global__ __launch_bounds__(256) void rope_pack(
    const short* __restrict__ QKV, const float2* __restrict__ trig,
    short* __restrict__ Kp, short* __restrict__ Vt) {
  const int blk = blockIdx.x;
  const int nt = blk & 15;
  const int h = (blk >> 4) & 15;
  const int b = blk >> 8;
  const int t = threadIdx.x;
  const int n0 = nt * 128;
  const long bhn = ((long)(b * NH + h)) * N_;

  for (int idx = t; idx < 128 * 48; idx += 256) {
    const int r = idx / 48;
    const int p = idx - r * 48;
    const int n = n0 + r;
    float vx = 0.f, vy = 0.f;
    if (p < 36) {
      short2 v2 = *(const short2*)(QKV + ((long)(b * N_ + n)) * QSTR + C_ + h * HD + 2 * p);
      vx = bf2f(v2.x); vy = bf2f(v2.y);
    }
    float o0 = vx, o1 = vy;
    if (p < 24) {
      const float2 cs = trig[n * 24 + p];
      o0 = vx * cs.x - vy * cs.y;
      o1 = vy * cs.x + vx * cs.y;
    }
    short2 ov; ov.x = f2bf(o0); ov.y = f2bf(o1);
    *(short2*)(Kp + (bhn + n) * HDP + 2 * p) = ov;
  }

  __shared__ short vt[128][82];
  for (int idx = t; idx < 128 * 40; idx += 256) {
    const int r = idx / 40, p = idx - r * 40;
    short2 v2; v2.x = 0; v2.y = 0;
    if (p < 36)
      v2 = *(const short2*)(QKV + ((long)(b * N_ + n0 + r)) * QSTR + 2 * C_ + h * HD + 2 * p);
    *(short2*)(&vt[r][2 * p]) = v2;
  }
  __syncthreads();
  for (int idx = t; idx < HDV * 128; idx += 256) {
    const int d = idx >> 7, nn = idx & 127;
    const int c = nn & 31;
    const int nsrc = (nn & 96) | (((c >> 2) & 1) * 16 + ((c >> 3) & 3) * 4 + (c & 3));
    Vt[(((long)(b * NH + h)) * HDV + d) * N_ + n0 + nn] = vt[nsrc][d];
  }
}

// ---------------- flash attention: triple-buffered KV + 2-deep s-pipeline, Q-RoPE via table ----------------
#define QKT_STEP(BUFI, S)                                                      \
  {                                                                            \
    const short* KsC_ = &KV[(BUFI)][0];                                        \
    __builtin_amdgcn_s_setprio(1);                                             \
    _Pragma("unroll")                                                          \
    for (int j = 0; j < 4; ++j) {                                              \
      _Pragma("unroll")                                                        \
      for (int kk = 0; kk < 3; ++kk) {                                         \
        bf16x8 kf = *(const bf16x8*)(KsC_ + (j * 16 + fr) * KROW + (kk * 4 + fq) * 8); \
        S[0][j] = __builtin_amdgcn_mfma_f32_16x16x32_bf16(kf, qf[0][kk], S[0][j], 0, 0, 0); \
        S[1][j] = __builtin_amdgcn_mfma_f32_16x16x32_bf16(kf, qf[1][kk], S[1][j], 0, 0, 0); \
      }                                                                        \
    }                                                                          \
    __builtin_amdgcn_s_setprio(0);                                             \
  }

#define ATTN_STEP(T, SCUR, SNEXT)                                              \
  {                                                                            \
    const int t_ = (T);                                                        \
    _Pragma("unroll")                                                          \
    for (int i = 0; i < 2; ++i) {                                              \
      float psum = 0.f;                                                        \
      _Pragma("unroll")                                                        \
      for (int j = 0; j < 4; ++j)                                              \
        _Pragma("unroll")                                                      \
        for (int r = 0; r < 4; ++r) {                                          \
          const float p = __builtin_amdgcn_exp2f(SCUR[i][j][r]);               \
          SCUR[i][j][r] = p;                                                   \
          psum += p;                                                           \
        }                                                                      \
      l_[i] += psum;                                                           \
    }                                                                          \
    asm volatile("s_waitcnt vmcnt(0)" ::: "memory");                           \
    __builtin_amdgcn_s_barrier();                                              \
    if (t_ + 2 < 32) STAGE(t_ + 2, (t_ + 2) % 3);                              \
    if (t_ + 1 < 32) {                                                         \
      _Pragma("unroll")                                                        \
      for (int i = 0; i < 2; ++i)                                              \
        _Pragma("unroll")                                                      \
        for (int j = 0; j < 4; ++j)                                            \
          SNEXT[i][j] = (f32x4){0.f, 0.f, 0.f, 0.f};                           \
      QKT_STEP((t_ + 1) % 3, SNEXT);                                           \
    }                                                                          \
    const short* VsC_ = &KV[t_ % 3][KCH * 8];                                  \
    __builtin_amdgcn_s_setprio(1);                                             \
    _Pragma("unroll")                                                          \
    for (int g = 0; g < 2; ++g) {                                              \
      union { unsigned u[4]; bf16x8 v; } pf0, pf1;                             \
      pf0.u[0] = pack_bf16(SCUR[0][2 * g][0],     SCUR[0][2 * g][1]);          \
      pf0.u[1] = pack_bf16(SCUR[0][2 * g][2],     SCUR[0][2 * g][3]);          \
      pf0.u[2] = pack_bf16(SCUR[0][2 * g + 1][0], SCUR[0][2 * g + 1][1]);      \
      pf0.u[3] = pack_bf16(SCUR[0][2 * g + 1][2], SCUR[0][2 * g + 1][3]);      \
      pf1.u[0] = pack_bf16(SCUR[1][2 * g][0],     SCUR[1][2 * g][1]);          \
      pf1.u[1] = pack_bf16(SCUR[1][2 * g][2],     SCUR[1][2 * g][3]);          \
      pf1.u[2] = pack_bf16(SCUR[1][2 * g + 1][0], SCUR[1][2 * g + 1][1]);      \
      pf1.u[3] = pack_bf16(SCUR[1][2 * g + 1][2], SCUR[1][2 * g + 1][3]);      \
      _Pragma("unroll")                                                        \
      for (int jd = 0; jd < 5; ++jd) {                                         \
        bf16x8 vf = *(const bf16x8*)(VsC_ + (jd * 16 + fr) * VROW + (g * 4 + fq) * 8); \
        accO[0][jd] = __builtin_amdgcn_mfma_f32_16x16x32_bf16(pf0.v, vf, accO[0][jd], 0, 0, 0); \
        accO[1][jd] = __builtin_amdgcn_mfma_f32_16x16x32_bf16(pf1.v, vf, accO[1][jd], 0, 0, 0); \
      }                                                                        \
    }                                                                          \
    __builtin_amdgcn_s_setprio(0);                                             \
  }

__global__ __launch_bounds__(256, 2) void attn(
    const short* __restrict__ QKVb, const short* __restrict__ Kp,
    const short* __restrict__ Vt, const float2* __restrict__ trig,
    short* __restrict__ Aproj) {
  __shared__ __align__(16) short KV[3][TCH * 8];  // 3 x 24.25 KB
  int blk = blockIdx.x;
  blk = (blk & 7) * 64 + (blk >> 3);
  const int qt = blk & 15;
  const int h = (blk >> 4) & 15;
  const int b = blk >> 8;
  const int t = threadIdx.x, lane = t & 63, wid = t >> 6;
  const int fr = lane & 15, fq = lane >> 4;

  const long bh = (long)(b * NH + h);
  const short* Kg = Kp + bh * N_ * HDP;
  const short* Vg = Vt + bh * HDV * N_;

  const short* sb[7];
  int sstr[7];
  #pragma unroll
  for (int it = 0; it < 7; ++it) {
    int g = wid * WCH + (it < 6 ? it * 64 + lane : 384 + lane);
    if (g >= TCH) g = TCH - 1;
    if (g < KCH) {
      const int r = g / 13, c = g - r * 13;
      sb[it] = Kg + r * HDP + (c < 12 ? c * 8 : 0);
      sstr[it] = KVB * HDP;
    } else {
      const int v = g - KCH;
      const int r = v / 9, c = v - r * 9;
      sb[it] = Vg + r * N_ + (c < 8 ? c * 8 : 0);
      sstr[it] = KVB;
    }
  }

  f32x4 accO[2][5] = {};
  float l_[2] = {0.f, 0.f};

  auto STAGE = [&](int kt, int bufi) {
    short* D = &KV[bufi][0];
    #pragma unroll
    for (int it = 0; it < 6; ++it)
      gload_lds16(sb[it] + kt * sstr[it], D + (wid * WCH + it * 64 + lane) * 8);
    if (lane < 4)
      gload_lds16(sb[6] + kt * sstr[6], D + (wid * WCH + 384 + lane) * 8);
  };

  // ---- Q staging into KV[2] (free until STAGE(2,2)) ----
  {
    short* QD = &KV[2][0];
    #pragma unroll
    for (int it = 0; it < 5; ++it) {
      const int g = wid * 288 + (it < 4 ? it * 64 + lane : 256 + (lane & 31));
      const int r = g / 9, c = g - r * 9;
      const short* src = QKVb + ((long)(b * N_ + qt * 128 + r)) * QSTR + h * HD + (c < 8 ? c * 8 : 64);
      if (it < 4 || lane < 32)
        gload_lds16(src, QD + g * 8);
    }
  }
  STAGE(0, 0);
  STAGE(1, 1);
  asm volatile("s_waitcnt vmcnt(14)" ::: "memory");  // Q's 5 loads landed
  __builtin_amdgcn_s_barrier();

  // ---- build qf from LDS Q tile; rope via precomputed trig table ----
  const float qscale = 0.17002324f;  // (1/sqrt(72)) * log2(e)
  bf16x8 qf[2][3];
  {
    const short* Qlds = &KV[2][0];
    #pragma unroll
    for (int i = 0; i < 2; ++i) {
      const int n = qt * 128 + wid * 32 + i * 16 + fr;
      const int lrow = wid * 32 + i * 16 + fr;
      #pragma unroll
      for (int kk = 0; kk < 3; ++kk) {
        const int col = kk * 32 + fq * 8;
        union { short s[8]; bf16x8 v; } raw;
        if (col < HD)
          raw.v = *(const bf16x8*)(Qlds + lrow * 72 + col);
        else
          #pragma unroll
          for (int z = 0; z < 8; ++z) raw.s[z] = 0;
        union { short s[8]; bf16x8 v; } outv;
        #pragma unroll
        for (int e = 0; e < 4; ++e) {
          const int p = kk * 16 + fq * 4 + e;
          const float vx = bf2f(raw.s[2 * e]), vy = bf2f(raw.s[2 * e + 1]);
          float o0 = vx, o1 = vy;
          if (p < 24) {
            const float2 cs = trig[n * 24 + p];
            o0 = vx * cs.x - vy * cs.y;
            o1 = vy * cs.x + vx * cs.y;
          }
          outv.s[2 * e]     = f2bf(o0 * qscale);
          outv.s[2 * e + 1] = f2bf(o1 * qscale);
        }
        qf[i][kk] = outv.v;
      }
    }
  }

  asm volatile("s_waitcnt vmcnt(7)" ::: "memory");  // tile-0 loads landed
  __builtin_amdgcn_s_barrier();                     // all waves done reading KV[2] as Q

  f32x4 sA[2][4], sB[2][4];
  #pragma unroll
  for (int i = 0; i < 2; ++i)
    #pragma unroll
    for (int j = 0; j < 4; ++j)
      sA[i][j] = (f32x4){0.f, 0.f, 0.f, 0.f};
  QKT_STEP(0, sA);

  for (int kt2 = 0; kt2 < 16; ++kt2) {
    ATTN_STEP(2 * kt2,     sA, sB);
    ATTN_STEP(2 * kt2 + 1, sB, sA);
  }

  #pragma unroll
  for (int i = 0; i < 2; ++i) {
    l_[i] += __shfl_xor(l_[i], 16);
    l_[i] += __shfl_xor(l_[i], 32);
  }
  float linv[2] = {1.f / l_[0], 1.f / l_[1]};
  #pragma unroll
  for (int i = 0; i < 2; ++i) {
    float li[4];
    #pragma unroll
    for (int r = 0; r < 4; ++r) li[r] = __shfl(linv[i], fq * 4 + r);
    #pragma unroll
    for (int r = 0; r < 4; ++r) {
      const long n = qt * 128 + wid * 32 + i * 16 + fq * 4 + r;
      #pragma unroll
      for (int jd = 0; jd < 5; ++jd) {
        const int d = jd * 16 + fr;
        if (d < HD)
          Aproj[((long)b * N_ + n) * C_ + h * HD + d] = f2bf(accO[i][jd][r] * li[r]);
      }
    }
  }
}

extern "C" void kernel_launch(void* const* d_in, const int* in_sizes, int n_in,
                              void* d_out, int out_size, void* d_ws, size_t ws_size,
                              hipStream_t stream) {
  const float* x     = (const float*)d_in[0];
  const float* Wqkv  = (const float*)d_in[1];
  const float* Wproj = (const float*)d_in[2];
  const float* bproj = (const float*)d_in[3];
  float* out = (float*)d_out;

  char* ws = (char*)d_ws;
  short* QKVb = (short*)ws;         size_t off = (size_t)4096 * QSTR * 2;
  short* xb  = (short*)(ws + off);  off += (size_t)4096 * 1152 * 2;
  short* Wt  = (short*)(ws + off);  off += (size_t)QSTR * 1152 * 2;
  short* Wpt = (short*)(ws + off);  off += (size_t)1152 * 1152 * 2;
  short* Kp  = (short*)(ws + off);  off += (size_t)B_ * NH * N_ * HDP * 2;
  short* Vt  = (short*)(ws + off);  off += (size_t)B_ * NH * HDV * N_ * 2;
  short* Ap  = (short*)(ws + off);  off += (size_t)4096 * 1152 * 2;
  float2* trig = (float2*)(ws + off);  off += (size_t)N_ * 24 * 8;

  prep<<<4608 + 4032 + 1296 + 192, 256, 0, stream>>>(x, xb, Wqkv, Wt, Wproj, Wpt, trig);
  gemm_bt256<<<dim3(QSTR / 256, 4096 / 256), 512, 0, stream>>>(
      xb, Wt, QKVb, 4096, QSTR, 1152);
  rope_pack<<<B_ * NH * (N_ / 128), 256, 0, stream>>>(QKVb, trig, Kp, Vt);
  attn<<<B_ * NH * (N_ / 128), 256, 0, stream>>>(QKVb, Kp, Vt, trig, Ap);
  gemm_bt<true, false><<<dim3(1152 / 128, 4096 / 128), 256, 0, stream>>>(
      Ap, Wpt, (void*)out, bproj, 4096, 1152, 1152);
}